// Round 12
// baseline (275.915 us; speedup 1.0000x reference)
//
#include <hip/hip_runtime.h>
#include <stdint.h>

// GNN: 2x GraphConv (norm='both') + attention gate + mean pooling + classifier.
// Round-19: round-18's cooperative build failed the harness (hipGraph capture
// + hipLaunchCooperativeKernel is the prime suspect; only new API). Revert to
// the proven round-17 structure (258.97us) with ONE capture-safe change:
// part_scatter was 196 blocks on 256 CUs (~12.5% occupancy, latency-bound
// scattered writes). Half-chunks: 392 count/scatter blocks of 4096 edges, u16
// histograms (fit existing slots), per-chunk int bases rewritten by the same
// 196-iter scan loop (bases aliased in colx's dead front). Scatter block h
// seeds cursor = base[h>>1] + (h&1 ? hist[h-1] : 0). History: 528 -> 415.7 ->
// 322.9 -> 297.8 -> 274.7 -> 270.0 -> 287.7 -> 280.7 -> 283.8 -> 258.97us.

#define N_NODES   100000
#define N_EDGES   1600000
#define N_GRAPHS  64
#define IN_DIM    128
#define HID       64
#define N_CLASSES 10

#define NBUCK     391       // ceil(100000/256) buckets of 256 nodes
#define CHUNKS    196       // scan-granularity chunks
#define HCHUNKS   392       // half-chunks (count/scatter blocks)
#define EPB_H     4096      // edges per half-chunk (392*4096 >= 1.6M)
#define GB_BLOCKS 391       // ceil(100000/256)
#define MTILES    6250      // 100000 / 16 nodes per wave-tile
#define GEMM_BLOCKS 1563    // ceil(6250/4) wave-tiles per 256-thr block
#define SPMM_BLOCKS 3125    // 100000 / 32 nodes per block (exact)
#define POOL_SLICES 32      // blocks per graph in pooling
#define WS_NEED   33885952u

typedef __attribute__((ext_vector_type(8))) short short8v;
typedef __attribute__((ext_vector_type(4))) float f32x4;
typedef __bf16 bf16x8 __attribute__((ext_vector_type(8)));

__device__ __forceinline__ f32x4 mfma16(short8v a, short8v b, f32x4 c) {
  return __builtin_amdgcn_mfma_f32_16x16x32_bf16(
      __builtin_bit_cast(bf16x8, a), __builtin_bit_cast(bf16x8, b), c, 0, 0, 0);
}

__device__ __forceinline__ float bf2f(unsigned short u) {
  unsigned int v = ((unsigned int)u) << 16;
  float f;
  __builtin_memcpy(&f, &v, 4);
  return f;
}

__device__ __forceinline__ unsigned short f2bf(float f) {
  unsigned int x;
  __builtin_memcpy(&x, &f, 4);
  unsigned int lsb = (x >> 16) & 1u;
  x += 0x7fffu + lsb;  // round-to-nearest-even
  return (unsigned short)(x >> 16);
}

__device__ __forceinline__ void unpack_bf2(unsigned int u, float& lo, float& hi) {
  unsigned int a = u << 16;
  unsigned int b = u & 0xffff0000u;
  __builtin_memcpy(&lo, &a, 4);
  __builtin_memcpy(&hi, &b, 4);
}

// mode: 1 = tensors are bf16, 0 = tensors are fp32
__device__ __forceinline__ float ldf(const void* p, int i, int mode) {
  return mode ? bf2f(((const unsigned short*)p)[i]) : ((const float*)p)[i];
}

// ---------------- fallback (ws too small): deterministic zero output ----------
__global__ __launch_bounds__(256) void fallback_kernel(unsigned short* __restrict__ out,
                                                       int n) {
  int i = blockIdx.x * 256 + threadIdx.x;
  if (i < n) out[i] = 0;
}

// ------- wcvt (with per-block self-probe of x's dtype) -----------------------
__global__ __launch_bounds__(256) void wcvt_kernel(
    const unsigned short* __restrict__ xu,
    const void* __restrict__ W1, const void* __restrict__ W2,
    const void* __restrict__ b1, const void* __restrict__ b2,
    const void* __restrict__ attnW, const void* __restrict__ attnb,
    const void* __restrict__ clsW, const void* __restrict__ clsb,
    unsigned short* __restrict__ W1hf, unsigned short* __restrict__ W1lf,
    unsigned short* __restrict__ W2hf, unsigned short* __restrict__ W2lf,
    float* __restrict__ b1f, float* __restrict__ b2f,
    float* __restrict__ attnWf, float* __restrict__ attnbf,
    float* __restrict__ clsWf, float* __restrict__ clsbf,
    int* __restrict__ flag) {
  __shared__ int cnt[4];
  __shared__ int smode;
  int tid = (int)threadIdx.x;
  unsigned u = xu[2 * tid];
  int e = (int)((u >> 7) & 0xFF);
  int ok = (e >= 110 && e <= 132) ? 1 : 0;
  unsigned long long m = __ballot(ok);
  if ((tid & 63) == 0) cnt[tid >> 6] = __popcll(m);
  __syncthreads();
  if (tid == 0) {
    smode = (cnt[0] + cnt[1] + cnt[2] + cnt[3] > 128) ? 1 : 0;
    if (blockIdx.x == 0) {
      flag[0] = smode;
      flag[1] = 1;
    }
  }
  __syncthreads();
  int mode = smode;

  int i = blockIdx.x * 256 + tid;
  if (i < 1024) {
    int tile = i >> 6, lane = i & 63;
    int kt = tile >> 2, ct = tile & 3;
#pragma unroll
    for (int j = 0; j < 8; ++j) {
      int k = kt * 32 + ((lane >> 4) << 3) + j;
      int d = (ct << 4) + (lane & 15);
      float v = ldf(W1, k * HID + d, mode);
      unsigned short h = f2bf(v);
      unsigned short l = f2bf(v - bf2f(h));
      W1hf[i * 8 + j] = h;
      W1lf[i * 8 + j] = l;
    }
  } else if (i < 1536) {
    int ii = i - 1024;
    int tile = ii >> 6, lane = ii & 63;
    int kt = tile >> 2, ct = tile & 3;
#pragma unroll
    for (int j = 0; j < 8; ++j) {
      int k = kt * 32 + ((lane >> 4) << 3) + j;
      int d = (ct << 4) + (lane & 15);
      float v = ldf(W2, k * HID + d, mode);
      unsigned short h = f2bf(v);
      unsigned short l = f2bf(v - bf2f(h));
      W2hf[ii * 8 + j] = h;
      W2lf[ii * 8 + j] = l;
    }
  }
  if (i < HID) {
    b1f[i] = ldf(b1, i, mode);
    b2f[i] = ldf(b2, i, mode);
    attnWf[i] = ldf(attnW, i, mode);
  }
  if (i == 0) attnbf[0] = ldf(attnb, 0, mode);
  if (i < HID * N_CLASSES) clsWf[i] = ldf(clsW, i, mode);
  if (i < N_CLASSES) clsbf[i] = ldf(clsb, i, mode);
}

// ====== MFMA GEMM tile body: 16 nodes x 64 dims per wave =====================
template <int K, bool SCALE>
__device__ __forceinline__ void gemm_tile(
    const void* __restrict__ A, const unsigned short* __restrict__ Whf,
    const unsigned short* __restrict__ Wlf, const float* __restrict__ norm_out,
    unsigned short* __restrict__ out, int mode, int mtile, int lane) {
  int n0 = mtile << 4;
  int row = lane & 15;
  int kg = lane >> 4;
  f32x4 acc0 = {0.f, 0.f, 0.f, 0.f};
  f32x4 acc1 = {0.f, 0.f, 0.f, 0.f};
  f32x4 acc2 = {0.f, 0.f, 0.f, 0.f};
  f32x4 acc3 = {0.f, 0.f, 0.f, 0.f};
  const short8v* whb0 = (const short8v*)Whf + lane;
  const short8v* wlb0 = (const short8v*)Wlf + lane;
  if (mode) {
    const unsigned short* xr = (const unsigned short*)A + (size_t)(n0 + row) * K + (kg << 3);
#pragma unroll
    for (int kt = 0; kt < K / 32; ++kt) {
      uint4 va = *(const uint4*)(xr + kt * 32);
      short8v xh = __builtin_bit_cast(short8v, va);
      const short8v* wh = whb0 + (size_t)(kt * 4) * 64;
      const short8v* wl = wlb0 + (size_t)(kt * 4) * 64;
      acc0 = mfma16(xh, wh[0], acc0);
      acc1 = mfma16(xh, wh[64], acc1);
      acc2 = mfma16(xh, wh[128], acc2);
      acc3 = mfma16(xh, wh[192], acc3);
      acc0 = mfma16(xh, wl[0], acc0);
      acc1 = mfma16(xh, wl[64], acc1);
      acc2 = mfma16(xh, wl[128], acc2);
      acc3 = mfma16(xh, wl[192], acc3);
    }
  } else {
    const float* xr = (const float*)A + (size_t)(n0 + row) * K + (kg << 3);
#pragma unroll
    for (int kt = 0; kt < K / 32; ++kt) {
      float4 a0 = *(const float4*)(xr + kt * 32);
      float4 a1 = *(const float4*)(xr + kt * 32 + 4);
      float xv[8] = {a0.x, a0.y, a0.z, a0.w, a1.x, a1.y, a1.z, a1.w};
      short8v xh, xl;
#pragma unroll
      for (int j = 0; j < 8; ++j) {
        unsigned short h = f2bf(xv[j]);
        unsigned short l = f2bf(xv[j] - bf2f(h));
        xh[j] = (short)h;
        xl[j] = (short)l;
      }
      const short8v* wh = whb0 + (size_t)(kt * 4) * 64;
      const short8v* wl = wlb0 + (size_t)(kt * 4) * 64;
      acc0 = mfma16(xh, wh[0], acc0);
      acc1 = mfma16(xh, wh[64], acc1);
      acc2 = mfma16(xh, wh[128], acc2);
      acc3 = mfma16(xh, wh[192], acc3);
      acc0 = mfma16(xh, wl[0], acc0);
      acc1 = mfma16(xh, wl[64], acc1);
      acc2 = mfma16(xh, wl[128], acc2);
      acc3 = mfma16(xh, wl[192], acc3);
      acc0 = mfma16(xl, wh[0], acc0);
      acc1 = mfma16(xl, wh[64], acc1);
      acc2 = mfma16(xl, wh[128], acc2);
      acc3 = mfma16(xl, wh[192], acc3);
    }
  }
  int col = lane & 15;
#pragma unroll
  for (int i = 0; i < 4; ++i) {
    int n = n0 + (kg << 2) + i;
    float s = SCALE ? norm_out[n] : 1.f;
    size_t rb = (size_t)n << 6;
    out[rb + col]      = f2bf(acc0[i] * s);
    out[rb + 16 + col] = f2bf(acc1[i] * s);
    out[rb + 32 + col] = f2bf(acc2[i] * s);
    out[rb + 48 + col] = f2bf(acc3[i] * s);
  }
}

// ====== FAT-A: half-chunk counts (u16) | gemm1_raw | gbound ==================
__global__ __launch_bounds__(256) void fatA_kernel(
    const int* __restrict__ ei, unsigned short* __restrict__ histD16,
    unsigned short* __restrict__ histS16,
    const int* __restrict__ gid, int* __restrict__ gstart,
    const void* __restrict__ x, const unsigned short* __restrict__ W1hf,
    const unsigned short* __restrict__ W1lf, unsigned short* __restrict__ bufA,
    const int* __restrict__ flag) {
  int b = (int)blockIdx.x;
  int t = (int)threadIdx.x;
  if (b < HCHUNKS) {
    __shared__ int hD[NBUCK];
    __shared__ int hS[NBUCK];
    for (int i = t; i < NBUCK; i += 256) { hD[i] = 0; hS[i] = 0; }
    __syncthreads();
    int base_e = b * EPB_H;
    for (int s = 0; s < EPB_H / 1024; ++s) {
      int e4 = base_e + s * 1024 + t * 4;
      if (e4 < N_EDGES) {
        int4 s4 = *(const int4*)(ei + e4);
        int4 d4 = *(const int4*)(ei + N_EDGES + e4);
        int ss[4] = {s4.x, s4.y, s4.z, s4.w};
        int dd[4] = {d4.x, d4.y, d4.z, d4.w};
#pragma unroll
        for (int j = 0; j < 4; ++j) {
          if ((unsigned)ss[j] < N_NODES) atomicAdd(&hS[ss[j] >> 8], 1);
          if ((unsigned)dd[j] < N_NODES) atomicAdd(&hD[dd[j] >> 8], 1);
        }
      }
    }
    __syncthreads();
    for (int i = t; i < NBUCK; i += 256) {
      histD16[b * NBUCK + i] = (unsigned short)hD[i];  // count <= 4096, fits
      histS16[b * NBUCK + i] = (unsigned short)hS[i];
    }
  } else if (b < HCHUNKS + GEMM_BLOCKS) {
    int mode = flag[0];
    int mtile = (b - HCHUNKS) * 4 + (t >> 6);
    if (mtile < MTILES)
      gemm_tile<IN_DIM, false>(x, W1hf, W1lf, (const float*)0, bufA, mode,
                               mtile, t & 63);
  } else {
    int bb = b - HCHUNKS - GEMM_BLOCKS;
    int n = bb * 256 + t;
    if (n >= N_NODES) return;
    int gc = gid[n] & (N_GRAPHS - 1);
    if (n == 0) {
      for (int g = 0; g <= gc; ++g) gstart[g] = 0;
    } else {
      int gp = gid[n - 1] & (N_GRAPHS - 1);
      for (int g = gp + 1; g <= gc; ++g) gstart[g] = n;
    }
    if (n == N_NODES - 1) {
      for (int g = gc + 1; g <= N_GRAPHS; ++g) gstart[g] = N_NODES;
    }
  }
}

// ====== P2: bucket totals over 392 halves + 391-scan + per-chunk int bases ===
__global__ __launch_bounds__(512) void bucket_scan_kernel(
    const unsigned short* __restrict__ histD16,
    const unsigned short* __restrict__ histS16,
    int* __restrict__ baseD, int* __restrict__ baseS,
    int* __restrict__ bstart_d, int* __restrict__ bstart_s) {
  const unsigned short* hist = (blockIdx.x == 0) ? histD16 : histS16;
  int* baseI = (blockIdx.x == 0) ? baseD : baseS;
  int* bst   = (blockIdx.x == 0) ? bstart_d : bstart_s;
  int u = (int)threadIdx.x;
  int tot = 0;
  if (u < NBUCK) {
    for (int h = 0; h < HCHUNKS; ++h) tot += (int)hist[h * NBUCK + u];
  }
  __shared__ int smA[512];
  __shared__ int smB[512];
  smA[u] = tot;
  __syncthreads();
  int* a = smA;
  int* bq = smB;
  for (int off = 1; off < 512; off <<= 1) {
    int v = a[u];
    if (u >= off) v += a[u - off];
    bq[u] = v;
    __syncthreads();
    int* tmp = a; a = bq; bq = tmp;
  }
  int excl = a[u] - tot;
  if (u <= NBUCK) bst[u] = excl;  // u==NBUCK: tot==0 -> excl == total
  if (u < NBUCK) {
    int off2 = excl;
    for (int c = 0; c < CHUNKS; ++c) {
      int cnt = (int)hist[(2 * c) * NBUCK + u] + (int)hist[(2 * c + 1) * NBUCK + u];
      baseI[c * NBUCK + u] = off2;
      off2 += cnt;
    }
  }
}

// =============== P3: scatter (392 half-chunk blocks) =========================
__global__ __launch_bounds__(256) void part_scatter_kernel(
    const int* __restrict__ ei, const int* __restrict__ baseD,
    const int* __restrict__ baseS,
    const unsigned short* __restrict__ histD16,
    const unsigned short* __restrict__ histS16,
    unsigned int* __restrict__ edstP, int* __restrict__ esrc) {
  __shared__ int cD[NBUCK];
  __shared__ int cS[NBUCK];
  int b = (int)blockIdx.x;
  int t = (int)threadIdx.x;
  int c = b >> 1;
  int odd = b & 1;
  for (int i = t; i < NBUCK; i += 256) {
    int bd = baseD[c * NBUCK + i];
    int bs = baseS[c * NBUCK + i];
    if (odd) {
      bd += (int)histD16[(b - 1) * NBUCK + i];  // even half's count
      bs += (int)histS16[(b - 1) * NBUCK + i];
    }
    cD[i] = bd;
    cS[i] = bs;
  }
  __syncthreads();
  int base_e = b * EPB_H;
  for (int s = 0; s < EPB_H / 1024; ++s) {
    int e4 = base_e + s * 1024 + t * 4;
    if (e4 < N_EDGES) {
      int4 s4 = *(const int4*)(ei + e4);
      int4 d4 = *(const int4*)(ei + N_EDGES + e4);
      int ss[4] = {s4.x, s4.y, s4.z, s4.w};
      int dd[4] = {d4.x, d4.y, d4.z, d4.w};
#pragma unroll
      for (int j = 0; j < 4; ++j) {
        if ((unsigned)ss[j] < N_NODES) {
          int slot = atomicAdd(&cS[ss[j] >> 8], 1);
          esrc[slot] = ss[j];
        }
        if ((unsigned)dd[j] < N_NODES) {
          int slot = atomicAdd(&cD[dd[j] >> 8], 1);
          edstP[slot] = ((unsigned int)ss[j] << 8) | ((unsigned int)dd[j] & 255u);
        }
      }
    }
  }
}

// =============== P4: per-bucket counting sort -> rowptr/col/norms ============
__global__ __launch_bounds__(256) void csr_kernel(
    const unsigned int* __restrict__ edstP, const int* __restrict__ esrc,
    const int* __restrict__ bstart_d, const int* __restrict__ bstart_s,
    int* __restrict__ rowptr, int* __restrict__ colx,
    float* __restrict__ norm_in, float* __restrict__ norm_out) {
  __shared__ int lc[256];
  __shared__ int smA[256];
  __shared__ int smB[256];
  int b = (int)blockIdx.x;
  int t = (int)threadIdx.x;
  if (b < NBUCK) {
    int node0 = b << 8;
    int base = bstart_d[b];
    int end  = bstart_d[b + 1];
    lc[t] = 0;
    __syncthreads();
    for (int i = base + t; i < end; i += 256) {
      unsigned int p = edstP[i];
      atomicAdd(&lc[p & 255u], 1);
    }
    __syncthreads();
    int my = lc[t];
    smA[t] = my;
    __syncthreads();
    int* a = smA;
    int* bq = smB;
    for (int off = 1; off < 256; off <<= 1) {
      int v = a[t];
      if (t >= off) v += a[t - off];
      bq[t] = v;
      __syncthreads();
      int* tmp = a; a = bq; bq = tmp;
    }
    int excl = a[t] - my;
    int n = node0 + t;
    if (n <= N_NODES) rowptr[n] = base + excl;
    if (n < N_NODES) {
      int c = my < 1 ? 1 : my;
      norm_in[n] = rsqrtf((float)c);
    }
    __syncthreads();
    lc[t] = base + excl;  // per-node cursor
    __syncthreads();
    for (int i = base + t; i < end; i += 256) {
      unsigned int p = edstP[i];
      int slot = atomicAdd(&lc[p & 255u], 1);
      colx[slot] = (int)(p >> 8);
    }
  } else {
    int bb = b - NBUCK;
    int node0 = bb << 8;
    int base = bstart_s[bb];
    int end  = bstart_s[bb + 1];
    lc[t] = 0;
    __syncthreads();
    for (int i = base + t; i < end; i += 256) {
      atomicAdd(&lc[esrc[i] - node0], 1);
    }
    __syncthreads();
    int n = node0 + t;
    if (n < N_NODES) {
      int c = lc[t] < 1 ? 1 : lc[t];
      norm_out[n] = rsqrtf((float)c);
    }
  }
}

// ------- SpMM core: 8 lanes per node, 4-deep unconditional gathers -----------
__device__ __forceinline__ void accum8f(uint4 v, float no, float acc[8]) {
  float lo, hi;
  unpack_bf2(v.x, lo, hi); acc[0] = fmaf(lo, no, acc[0]); acc[1] = fmaf(hi, no, acc[1]);
  unpack_bf2(v.y, lo, hi); acc[2] = fmaf(lo, no, acc[2]); acc[3] = fmaf(hi, no, acc[3]);
  unpack_bf2(v.z, lo, hi); acc[4] = fmaf(lo, no, acc[4]); acc[5] = fmaf(hi, no, acc[5]);
  unpack_bf2(v.w, lo, hi); acc[6] = fmaf(lo, no, acc[6]); acc[7] = fmaf(hi, no, acc[7]);
}

// gather with per-src norm_out scale; cols guaranteed valid by our CSR build
__device__ __forceinline__ void spmm_gather8s(const unsigned short* __restrict__ hs,
                                              const int* __restrict__ col,
                                              const float* __restrict__ no,
                                              int e0, int e1, int dim0,
                                              float acc[8]) {
  int e = e0;
  for (; e + 4 <= e1; e += 4) {
    int c0 = col[e], c1 = col[e + 1], c2 = col[e + 2], c3 = col[e + 3];
    float n0 = no[c0], n1 = no[c1], n2 = no[c2], n3 = no[c3];
    uint4 v0 = *(const uint4*)(hs + ((size_t)c0 << 6) + dim0);
    uint4 v1 = *(const uint4*)(hs + ((size_t)c1 << 6) + dim0);
    uint4 v2 = *(const uint4*)(hs + ((size_t)c2 << 6) + dim0);
    uint4 v3 = *(const uint4*)(hs + ((size_t)c3 << 6) + dim0);
    accum8f(v0, n0, acc);
    accum8f(v1, n1, acc);
    accum8f(v2, n2, acc);
    accum8f(v3, n3, acc);
  }
  for (; e < e1; ++e) {
    int c = col[e];
    uint4 v = *(const uint4*)(hs + ((size_t)c << 6) + dim0);
    accum8f(v, no[c], acc);
  }
}

__device__ __forceinline__ void accum8(uint4 v, float acc[8]) {
  float lo, hi;
  unpack_bf2(v.x, lo, hi); acc[0] += lo; acc[1] += hi;
  unpack_bf2(v.y, lo, hi); acc[2] += lo; acc[3] += hi;
  unpack_bf2(v.z, lo, hi); acc[4] += lo; acc[5] += hi;
  unpack_bf2(v.w, lo, hi); acc[6] += lo; acc[7] += hi;
}

__device__ __forceinline__ void spmm_gather8(const unsigned short* __restrict__ hs,
                                             const int* __restrict__ col,
                                             int e0, int e1, int dim0,
                                             float acc[8]) {
  int e = e0;
  for (; e + 4 <= e1; e += 4) {
    int c0 = col[e], c1 = col[e + 1], c2 = col[e + 2], c3 = col[e + 3];
    uint4 v0 = *(const uint4*)(hs + ((size_t)c0 << 6) + dim0);
    uint4 v1 = *(const uint4*)(hs + ((size_t)c1 << 6) + dim0);
    uint4 v2 = *(const uint4*)(hs + ((size_t)c2 << 6) + dim0);
    uint4 v3 = *(const uint4*)(hs + ((size_t)c3 << 6) + dim0);
    accum8(v0, acc);
    accum8(v1, acc);
    accum8(v2, acc);
    accum8(v3, acc);
  }
  for (; e < e1; ++e) {
    int c = col[e];
    uint4 v = *(const uint4*)(hs + ((size_t)c << 6) + dim0);
    accum8(v, acc);
  }
}

// ====== Fused SpMM layer-1 + gemm2: block = 32 nodes =========================
__global__ __launch_bounds__(256) void spmm_gemm_kernel(
    const unsigned short* __restrict__ hs,
    const int* __restrict__ rowptr, const int* __restrict__ col,
    const float* __restrict__ norm_out, const float* __restrict__ norm_in,
    const float* __restrict__ b1f,
    const unsigned short* __restrict__ W2hf,
    const unsigned short* __restrict__ W2lf,
    unsigned short* __restrict__ hs2) {
  __shared__ unsigned short h1s[32][72];  // 72 = 64 + 8 pad
  int t = (int)threadIdx.x;
  // ---- phase 1: SpMM (grid is exact: 3125*32 == 100000, no tail) ----
  int n = (int)blockIdx.x * 32 + (t >> 3);
  int dim0 = (t & 7) << 3;
  int e0 = rowptr[n], e1 = rowptr[n + 1];
  if (e0 < 0) e0 = 0;
  if (e1 > N_EDGES) e1 = N_EDGES;
  float acc[8];
#pragma unroll
  for (int i = 0; i < 8; ++i) acc[i] = 0.f;
  spmm_gather8s(hs, col, norm_out, e0, e1, dim0, acc);
  float nin = norm_in[n];
  unsigned int pk[4];
#pragma unroll
  for (int i = 0; i < 4; ++i) {
    float vlo = fmaxf(acc[2 * i] * nin + b1f[dim0 + 2 * i], 0.f);
    float vhi = fmaxf(acc[2 * i + 1] * nin + b1f[dim0 + 2 * i + 1], 0.f);
    pk[i] = (unsigned int)f2bf(vlo) | ((unsigned int)f2bf(vhi) << 16);
  }
  *(uint4*)&h1s[t >> 3][dim0] = make_uint4(pk[0], pk[1], pk[2], pk[3]);
  __syncthreads();
  // ---- phase 2: MFMA h1 @ W2 ----
  int wv = t >> 6;             // wave 0..3
  int lane = t & 63;
  int mloc = (wv >> 1) << 4;   // node sub-tile 0 or 16
  int ct0 = (wv & 1) << 1;     // col-tiles {0,1} or {2,3}
  int row = lane & 15, kg = lane >> 4;
  f32x4 a0 = {0.f, 0.f, 0.f, 0.f};
  f32x4 a1 = {0.f, 0.f, 0.f, 0.f};
  const short8v* wh = (const short8v*)W2hf + lane;
  const short8v* wl = (const short8v*)W2lf + lane;
#pragma unroll
  for (int kt = 0; kt < 2; ++kt) {
    short8v av = *(const short8v*)&h1s[mloc + row][kt * 32 + (kg << 3)];
    a0 = mfma16(av, wh[(kt * 4 + ct0) * 64], a0);
    a1 = mfma16(av, wh[(kt * 4 + ct0 + 1) * 64], a1);
    a0 = mfma16(av, wl[(kt * 4 + ct0) * 64], a0);
    a1 = mfma16(av, wl[(kt * 4 + ct0 + 1) * 64], a1);
  }
  int colc = lane & 15;
#pragma unroll
  for (int i = 0; i < 4; ++i) {
    int ng = (int)blockIdx.x * 32 + mloc + (kg << 2) + i;
    float s = norm_out[ng];
    size_t rb = (size_t)ng << 6;
    hs2[rb + (ct0 << 4) + colc]       = f2bf(a0[i] * s);
    hs2[rb + ((ct0 + 1) << 4) + colc] = f2bf(a1[i] * s);
  }
}

// ------- SpMM layer-2 fused with attention gate; 8 lanes per node ------------
__global__ __launch_bounds__(256) void spmm_attn_kernel(
    const unsigned short* __restrict__ hs,
    const int* __restrict__ rowptr, const int* __restrict__ col,
    const float* __restrict__ norm_in, const float* __restrict__ b2f,
    const float* __restrict__ attnWf, const float* __restrict__ attnbf,
    void* __restrict__ out_base, unsigned short* __restrict__ gated,
    const int* __restrict__ flag) {
  int mode = flag[0];
  int n = (int)(blockIdx.x * 32 + (threadIdx.x >> 3));
  int dim0 = ((int)threadIdx.x & 7) << 3;
  if (n >= N_NODES) return;
  int e0 = rowptr[n], e1 = rowptr[n + 1];
  if (e0 < 0) e0 = 0;
  if (e1 > N_EDGES) e1 = N_EDGES;
  float acc[8];
#pragma unroll
  for (int i = 0; i < 8; ++i) acc[i] = 0.f;
  spmm_gather8(hs, col, e0, e1, dim0, acc);
  float nin = norm_in[n];
  float vv[8];
  float p = 0.f;
#pragma unroll
  for (int i = 0; i < 8; ++i) {
    vv[i] = fmaxf(acc[i] * nin + b2f[dim0 + i], 0.f);  // h2[n][dim0+i]
    p += vv[i] * attnWf[dim0 + i];
  }
#pragma unroll
  for (int m = 1; m <= 4; m <<= 1) p += __shfl_xor(p, m, 64);
  float logit = p + attnbf[0];
  float hwv = 1.f / (1.f + __expf(-logit));
  if ((threadIdx.x & 7) == 0) {
    if (mode) ((unsigned short*)out_base)[N_GRAPHS * N_CLASSES + n] = f2bf(hwv);
    else      ((float*)out_base)[N_GRAPHS * N_CLASSES + n] = hwv;
  }
  unsigned int pk[4];
#pragma unroll
  for (int i = 0; i < 4; ++i) {
    pk[i] = (unsigned int)f2bf(vv[2 * i] * hwv) |
            ((unsigned int)f2bf(vv[2 * i + 1] * hwv) << 16);
  }
  *(uint4*)(gated + ((size_t)n << 6) + dim0) = make_uint4(pk[0], pk[1], pk[2], pk[3]);
}

// -------- pool: 64 graphs x 32 slices, partial sums ----------
__global__ __launch_bounds__(256) void pool_kernel(const unsigned short* __restrict__ gated,
                                                   const int* __restrict__ gstart,
                                                   float* __restrict__ gpart) {
  int g = (int)blockIdx.x >> 5;         // graph
  int s = (int)blockIdx.x & 31;         // slice
  int dim = (int)threadIdx.x & 63;
  int rsel = (int)threadIdx.x >> 6;
  int r0 = gstart[g], r1 = gstart[g + 1];
  if (r0 < 0) r0 = 0;
  if (r1 > N_NODES) r1 = N_NODES;
  int len = r1 - r0;
  if (len < 0) len = 0;
  int a = r0 + (int)(((long long)len * s) >> 5);
  int bnd = r0 + (int)(((long long)len * (s + 1)) >> 5);
  float acc = 0.f;
  for (int r = a + rsel; r < bnd; r += 4)
    acc += bf2f(gated[((size_t)r << 6) + dim]);
  __shared__ float sm[256];
  sm[threadIdx.x] = acc;
  __syncthreads();
  if (threadIdx.x < 64)
    gpart[((size_t)blockIdx.x << 6) + dim] =
        sm[dim] + sm[64 + dim] + sm[128 + dim] + sm[192 + dim];
}

// ---- final (merged slice-reduce + classifier): 1 block, 640 threads ---------
__global__ __launch_bounds__(640) void final_kernel(const float* __restrict__ gpart,
                                                    const int* __restrict__ gstart,
                                                    const float* __restrict__ clsWf,
                                                    const float* __restrict__ clsbf,
                                                    void* __restrict__ out_base,
                                                    const int* __restrict__ flag) {
  __shared__ float gs[N_GRAPHS * HID];
  int t = (int)threadIdx.x;
  for (int idx = t; idx < N_GRAPHS * HID; idx += 640) {
    int g = idx >> 6, d = idx & 63;
    float a = 0.f;
#pragma unroll
    for (int s = 0; s < POOL_SLICES; ++s)
      a += gpart[(((size_t)(g << 5) + s) << 6) + d];
    gs[idx] = a;
  }
  __syncthreads();
  int mode = flag[0];
  if (t >= N_GRAPHS * N_CLASSES) return;
  int g = t / N_CLASSES, c = t - g * N_CLASSES;
  int cg = gstart[g + 1] - gstart[g];
  if (cg < 1) cg = 1;
  float inv = 1.f / (float)cg;
  float acc = 0.f;
#pragma unroll
  for (int d = 0; d < HID; ++d) acc += gs[(g << 6) + d] * clsWf[d * N_CLASSES + c];
  float r = acc * inv + clsbf[c];
  if (mode) ((unsigned short*)out_base)[t] = f2bf(r);
  else      ((float*)out_base)[t] = r;
}

extern "C" void kernel_launch(void* const* d_in, const int* in_sizes, int n_in,
                              void* d_out, int out_size, void* d_ws, size_t ws_size,
                              hipStream_t stream) {
  const void* x     = d_in[0];
  const int*  ei    = (const int*)d_in[1];
  const int*  gid   = (const int*)d_in[2];
  const void* W1    = d_in[3];
  const void* b1    = d_in[4];
  const void* W2    = d_in[5];
  const void* b2    = d_in[6];
  const void* attnW = d_in[7];
  const void* attnb = d_in[8];
  const void* clsW  = d_in[9];
  const void* clsb  = d_in[10];

  if (ws_size < (size_t)WS_NEED) {
    fallback_kernel<<<(out_size + 255) / 256, 256, 0, stream>>>(
        (unsigned short*)d_out, out_size);
    return;
  }

  // ---- workspace layout (bytes). Every buffer fully written by a producer. ----
  char* w = (char*)d_ws;
  int*   flag     = (int*)(w + 0);          //      64 (2 used, wcvt writes)
  int*   gstart   = (int*)(w + 64);         //     512 (gbound writes all)
  int*   bstart_d = (int*)(w + 16960);      //    1600 (392 used)
  int*   bstart_s = (int*)(w + 18560);      //    1600
  unsigned short* histD16 = (unsigned short*)(w + 20160);   // 392*391*2=306544
  unsigned short* histS16 = (unsigned short*)(w + 326720);  // 306544
  int*   rowptr   = (int*)(w + 633280);     //  400064 (100001 used)
  float* norm_out = (float*)(w + 1033344);  //  400000
  float* norm_in  = (float*)(w + 1433344);  //  400000
  unsigned short* W1hf = (unsigned short*)(w + 1833344);  // 16384
  unsigned short* W1lf = (unsigned short*)(w + 1849728);  // 16384
  unsigned short* W2hf = (unsigned short*)(w + 1866112);  //  8192
  unsigned short* W2lf = (unsigned short*)(w + 1874304);  //  8192 -> 1882496
  float* b1f      = (float*)(w + 1882496);  //     256
  float* b2f      = (float*)(w + 1882752);  //     256
  float* attnWf   = (float*)(w + 1883008);  //     256
  float* attnbf   = (float*)(w + 1883264);  //      64
  float* clsWf    = (float*)(w + 1883328);  //    2560
  float* clsbf    = (float*)(w + 1885888);  //      64 -> 1885952
  int*   colx     = (int*)(w + 1885952);    //  6400000 -> 8285952
  // per-chunk int bases alias colx's dead front (written by scan, read by
  // scatter; csr overwrites colx only after scatter's last read).
  int*   baseD    = (int*)(w + 1885952);              // 196*391*4 = 306560
  int*   baseS    = (int*)(w + 1885952 + 306560);     // 306560 -> 2499072
  unsigned int* edstP = (unsigned int*)(w + 8285952);   // 6400000 -> 14685952
  int*   esrc     = (int*)(w + 14685952);   //  6400000 -> 21085952
  unsigned short* bufA = (unsigned short*)(w + 21085952); // 12800000 -> 33885952
  // bufB aliases edstP+esrc (dead after csr; spmm_gemm writes after csr).
  unsigned short* bufB = (unsigned short*)(w + 8285952);  // 12800000
  // gpart aliases hist region (dead after scatter; pool writes after spmm_attn)
  float* gpart    = (float*)(w + 20160);    // 524288 <= 613120 available

  // wcvt self-probes x's dtype and writes flag; converts weights to fragments.
  wcvt_kernel<<<32, 256, 0, stream>>>((const unsigned short*)x, W1, W2, b1, b2,
                                      attnW, attnb, clsW, clsb, W1hf, W1lf,
                                      W2hf, W2lf, b1f, b2f, attnWf, attnbf,
                                      clsWf, clsbf, flag);

  // FAT-A: half-chunk u16 histograms | gemm1_raw (MFMA) | graph bounds
  fatA_kernel<<<HCHUNKS + GEMM_BLOCKS + GB_BLOCKS, 256, 0, stream>>>(
      ei, histD16, histS16, gid, gstart, x, W1hf, W1lf, bufA, flag);

  // scan: totals over 392 halves + 391-scan + per-chunk int base rewrite
  bucket_scan_kernel<<<2, 512, 0, stream>>>(histD16, histS16, baseD, baseS,
                                            bstart_d, bstart_s);
  // scatter: 392 half-chunk blocks (2x occupancy vs 196)
  part_scatter_kernel<<<HCHUNKS, 256, 0, stream>>>(ei, baseD, baseS, histD16,
                                                   histS16, edstP, esrc);
  csr_kernel<<<2 * NBUCK, 256, 0, stream>>>(edstP, esrc, bstart_d, bstart_s,
                                            rowptr, colx, norm_in, norm_out);

  // fused layer-1 SpMM + gemm2: bufA (hs1raw) -> bufB (hs2), via LDS h1 tile
  spmm_gemm_kernel<<<SPMM_BLOCKS, 256, 0, stream>>>(
      bufA, rowptr, colx, norm_out, norm_in, b1f, W2hf, W2lf, bufB);

  // layer-2 aggregation + attention gate: bufB (hs2) -> bufA (gated rows)
  spmm_attn_kernel<<<SPMM_BLOCKS, 256, 0, stream>>>(
      bufB, rowptr, colx, norm_in, b2f, attnWf, attnbf, d_out, bufA, flag);

  // pooling: 2048 slice blocks -> partials; final merges reduce + classifier
  pool_kernel<<<N_GRAPHS * POOL_SLICES, 256, 0, stream>>>(bufA, gstart, gpart);
  final_kernel<<<1, 640, 0, stream>>>(gpart, gstart, clsWf, clsbf, d_out, flag);
}

// Round 13
// 257.211 us; speedup vs baseline: 1.0727x; 1.0727x over previous
//
#include <hip/hip_runtime.h>
#include <stdint.h>

// GNN: 2x GraphConv (norm='both') + attention gate + mean pooling + classifier.
// Round-20: FINAL — byte-identical restore of the verified best (round-17
// config, measured 258.97us). Rounds 14-16 and 18-19 each perturbed the build
// chain or spmm inner loop and ALL regressed (-17..-29us); the wins were:
// atomic-free bucket build, split pooling, 8-lane spmm, MFMA gemms (hi/lo
// bf16 split), fatA co-dispatch, and gemm2 fused into spmm1 via LDS.
// History: 528 -> 415.7 -> 322.9 -> 297.8 -> 274.7 -> 270.0 -> 287.7 ->
// 280.7 -> 283.8 -> 258.97 (best) -> fail -> 275.9 -> restore.

#define N_NODES   100000
#define N_EDGES   1600000
#define N_GRAPHS  64
#define IN_DIM    128
#define HID       64
#define N_CLASSES 10

#define NBUCK     391       // ceil(100000/256) buckets of 256 nodes
#define P1B       196       // partition chunk blocks
#define EPB       8192      // edges per chunk block (196*8192 >= 1.6M)
#define GB_BLOCKS 391       // ceil(100000/256)
#define MTILES    6250      // 100000 / 16 nodes per wave-tile
#define GEMM_BLOCKS 1563    // ceil(6250/4) wave-tiles per 256-thr block
#define SPMM_BLOCKS 3125    // 100000 / 32 nodes per block (exact)
#define POOL_SLICES 32      // blocks per graph in pooling
#define WS_NEED   33885952u

typedef __attribute__((ext_vector_type(8))) short short8v;
typedef __attribute__((ext_vector_type(4))) float f32x4;
typedef __bf16 bf16x8 __attribute__((ext_vector_type(8)));

__device__ __forceinline__ f32x4 mfma16(short8v a, short8v b, f32x4 c) {
  return __builtin_amdgcn_mfma_f32_16x16x32_bf16(
      __builtin_bit_cast(bf16x8, a), __builtin_bit_cast(bf16x8, b), c, 0, 0, 0);
}

__device__ __forceinline__ float bf2f(unsigned short u) {
  unsigned int v = ((unsigned int)u) << 16;
  float f;
  __builtin_memcpy(&f, &v, 4);
  return f;
}

__device__ __forceinline__ unsigned short f2bf(float f) {
  unsigned int x;
  __builtin_memcpy(&x, &f, 4);
  unsigned int lsb = (x >> 16) & 1u;
  x += 0x7fffu + lsb;  // round-to-nearest-even
  return (unsigned short)(x >> 16);
}

__device__ __forceinline__ void unpack_bf2(unsigned int u, float& lo, float& hi) {
  unsigned int a = u << 16;
  unsigned int b = u & 0xffff0000u;
  __builtin_memcpy(&lo, &a, 4);
  __builtin_memcpy(&hi, &b, 4);
}

// mode: 1 = tensors are bf16, 0 = tensors are fp32
__device__ __forceinline__ float ldf(const void* p, int i, int mode) {
  return mode ? bf2f(((const unsigned short*)p)[i]) : ((const float*)p)[i];
}

// ---------------- fallback (ws too small): deterministic zero output ----------
__global__ __launch_bounds__(256) void fallback_kernel(unsigned short* __restrict__ out,
                                                       int n) {
  int i = blockIdx.x * 256 + threadIdx.x;
  if (i < n) out[i] = 0;
}

// ------- wcvt (with per-block self-probe of x's dtype) -----------------------
__global__ __launch_bounds__(256) void wcvt_kernel(
    const unsigned short* __restrict__ xu,
    const void* __restrict__ W1, const void* __restrict__ W2,
    const void* __restrict__ b1, const void* __restrict__ b2,
    const void* __restrict__ attnW, const void* __restrict__ attnb,
    const void* __restrict__ clsW, const void* __restrict__ clsb,
    unsigned short* __restrict__ W1hf, unsigned short* __restrict__ W1lf,
    unsigned short* __restrict__ W2hf, unsigned short* __restrict__ W2lf,
    float* __restrict__ b1f, float* __restrict__ b2f,
    float* __restrict__ attnWf, float* __restrict__ attnbf,
    float* __restrict__ clsWf, float* __restrict__ clsbf,
    int* __restrict__ flag) {
  __shared__ int cnt[4];
  __shared__ int smode;
  int tid = (int)threadIdx.x;
  unsigned u = xu[2 * tid];
  int e = (int)((u >> 7) & 0xFF);
  int ok = (e >= 110 && e <= 132) ? 1 : 0;
  unsigned long long m = __ballot(ok);
  if ((tid & 63) == 0) cnt[tid >> 6] = __popcll(m);
  __syncthreads();
  if (tid == 0) {
    smode = (cnt[0] + cnt[1] + cnt[2] + cnt[3] > 128) ? 1 : 0;
    if (blockIdx.x == 0) {
      flag[0] = smode;
      flag[1] = 1;
    }
  }
  __syncthreads();
  int mode = smode;

  int i = blockIdx.x * 256 + tid;
  if (i < 1024) {
    int tile = i >> 6, lane = i & 63;
    int kt = tile >> 2, ct = tile & 3;
#pragma unroll
    for (int j = 0; j < 8; ++j) {
      int k = kt * 32 + ((lane >> 4) << 3) + j;
      int d = (ct << 4) + (lane & 15);
      float v = ldf(W1, k * HID + d, mode);
      unsigned short h = f2bf(v);
      unsigned short l = f2bf(v - bf2f(h));
      W1hf[i * 8 + j] = h;
      W1lf[i * 8 + j] = l;
    }
  } else if (i < 1536) {
    int ii = i - 1024;
    int tile = ii >> 6, lane = ii & 63;
    int kt = tile >> 2, ct = tile & 3;
#pragma unroll
    for (int j = 0; j < 8; ++j) {
      int k = kt * 32 + ((lane >> 4) << 3) + j;
      int d = (ct << 4) + (lane & 15);
      float v = ldf(W2, k * HID + d, mode);
      unsigned short h = f2bf(v);
      unsigned short l = f2bf(v - bf2f(h));
      W2hf[ii * 8 + j] = h;
      W2lf[ii * 8 + j] = l;
    }
  }
  if (i < HID) {
    b1f[i] = ldf(b1, i, mode);
    b2f[i] = ldf(b2, i, mode);
    attnWf[i] = ldf(attnW, i, mode);
  }
  if (i == 0) attnbf[0] = ldf(attnb, 0, mode);
  if (i < HID * N_CLASSES) clsWf[i] = ldf(clsW, i, mode);
  if (i < N_CLASSES) clsbf[i] = ldf(clsb, i, mode);
}

// ====== MFMA GEMM tile body: 16 nodes x 64 dims per wave =====================
template <int K, bool SCALE>
__device__ __forceinline__ void gemm_tile(
    const void* __restrict__ A, const unsigned short* __restrict__ Whf,
    const unsigned short* __restrict__ Wlf, const float* __restrict__ norm_out,
    unsigned short* __restrict__ out, int mode, int mtile, int lane) {
  int n0 = mtile << 4;
  int row = lane & 15;
  int kg = lane >> 4;
  f32x4 acc0 = {0.f, 0.f, 0.f, 0.f};
  f32x4 acc1 = {0.f, 0.f, 0.f, 0.f};
  f32x4 acc2 = {0.f, 0.f, 0.f, 0.f};
  f32x4 acc3 = {0.f, 0.f, 0.f, 0.f};
  const short8v* whb0 = (const short8v*)Whf + lane;
  const short8v* wlb0 = (const short8v*)Wlf + lane;
  if (mode) {
    const unsigned short* xr = (const unsigned short*)A + (size_t)(n0 + row) * K + (kg << 3);
#pragma unroll
    for (int kt = 0; kt < K / 32; ++kt) {
      uint4 va = *(const uint4*)(xr + kt * 32);
      short8v xh = __builtin_bit_cast(short8v, va);
      const short8v* wh = whb0 + (size_t)(kt * 4) * 64;
      const short8v* wl = wlb0 + (size_t)(kt * 4) * 64;
      acc0 = mfma16(xh, wh[0], acc0);
      acc1 = mfma16(xh, wh[64], acc1);
      acc2 = mfma16(xh, wh[128], acc2);
      acc3 = mfma16(xh, wh[192], acc3);
      acc0 = mfma16(xh, wl[0], acc0);
      acc1 = mfma16(xh, wl[64], acc1);
      acc2 = mfma16(xh, wl[128], acc2);
      acc3 = mfma16(xh, wl[192], acc3);
    }
  } else {
    const float* xr = (const float*)A + (size_t)(n0 + row) * K + (kg << 3);
#pragma unroll
    for (int kt = 0; kt < K / 32; ++kt) {
      float4 a0 = *(const float4*)(xr + kt * 32);
      float4 a1 = *(const float4*)(xr + kt * 32 + 4);
      float xv[8] = {a0.x, a0.y, a0.z, a0.w, a1.x, a1.y, a1.z, a1.w};
      short8v xh, xl;
#pragma unroll
      for (int j = 0; j < 8; ++j) {
        unsigned short h = f2bf(xv[j]);
        unsigned short l = f2bf(xv[j] - bf2f(h));
        xh[j] = (short)h;
        xl[j] = (short)l;
      }
      const short8v* wh = whb0 + (size_t)(kt * 4) * 64;
      const short8v* wl = wlb0 + (size_t)(kt * 4) * 64;
      acc0 = mfma16(xh, wh[0], acc0);
      acc1 = mfma16(xh, wh[64], acc1);
      acc2 = mfma16(xh, wh[128], acc2);
      acc3 = mfma16(xh, wh[192], acc3);
      acc0 = mfma16(xh, wl[0], acc0);
      acc1 = mfma16(xh, wl[64], acc1);
      acc2 = mfma16(xh, wl[128], acc2);
      acc3 = mfma16(xh, wl[192], acc3);
      acc0 = mfma16(xl, wh[0], acc0);
      acc1 = mfma16(xl, wh[64], acc1);
      acc2 = mfma16(xl, wh[128], acc2);
      acc3 = mfma16(xl, wh[192], acc3);
    }
  }
  int col = lane & 15;
#pragma unroll
  for (int i = 0; i < 4; ++i) {
    int n = n0 + (kg << 2) + i;
    float s = SCALE ? norm_out[n] : 1.f;
    size_t rb = (size_t)n << 6;
    out[rb + col]      = f2bf(acc0[i] * s);
    out[rb + 16 + col] = f2bf(acc1[i] * s);
    out[rb + 32 + col] = f2bf(acc2[i] * s);
    out[rb + 48 + col] = f2bf(acc3[i] * s);
  }
}

// ====== FAT-A: part_count | gemm1_raw (unscaled x@W1) | gbound ===============
__global__ __launch_bounds__(256) void fatA_kernel(
    const int* __restrict__ ei, int* __restrict__ blkhistD,
    int* __restrict__ blkhistS,
    const int* __restrict__ gid, int* __restrict__ gstart,
    const void* __restrict__ x, const unsigned short* __restrict__ W1hf,
    const unsigned short* __restrict__ W1lf, unsigned short* __restrict__ bufA,
    const int* __restrict__ flag) {
  int b = (int)blockIdx.x;
  int t = (int)threadIdx.x;
  if (b < P1B) {
    __shared__ int hD[NBUCK];
    __shared__ int hS[NBUCK];
    for (int i = t; i < NBUCK; i += 256) { hD[i] = 0; hS[i] = 0; }
    __syncthreads();
    int base_e = b * EPB;
    for (int s = 0; s < EPB / 1024; ++s) {
      int e4 = base_e + s * 1024 + t * 4;
      if (e4 < N_EDGES) {
        int4 s4 = *(const int4*)(ei + e4);
        int4 d4 = *(const int4*)(ei + N_EDGES + e4);
        int ss[4] = {s4.x, s4.y, s4.z, s4.w};
        int dd[4] = {d4.x, d4.y, d4.z, d4.w};
#pragma unroll
        for (int j = 0; j < 4; ++j) {
          if ((unsigned)ss[j] < N_NODES) atomicAdd(&hS[ss[j] >> 8], 1);
          if ((unsigned)dd[j] < N_NODES) atomicAdd(&hD[dd[j] >> 8], 1);
        }
      }
    }
    __syncthreads();
    for (int i = t; i < NBUCK; i += 256) {
      blkhistD[b * NBUCK + i] = hD[i];
      blkhistS[b * NBUCK + i] = hS[i];
    }
  } else if (b < P1B + GEMM_BLOCKS) {
    int mode = flag[0];
    int mtile = (b - P1B) * 4 + (t >> 6);
    if (mtile < MTILES)
      gemm_tile<IN_DIM, false>(x, W1hf, W1lf, (const float*)0, bufA, mode,
                               mtile, t & 63);
  } else {
    int bb = b - P1B - GEMM_BLOCKS;
    int n = bb * 256 + t;
    if (n >= N_NODES) return;
    int gc = gid[n] & (N_GRAPHS - 1);
    if (n == 0) {
      for (int g = 0; g <= gc; ++g) gstart[g] = 0;
    } else {
      int gp = gid[n - 1] & (N_GRAPHS - 1);
      for (int g = gp + 1; g <= gc; ++g) gstart[g] = n;
    }
    if (n == N_NODES - 1) {
      for (int g = gc + 1; g <= N_GRAPHS; ++g) gstart[g] = N_NODES;
    }
  }
}

// =============== P2: bucket totals scan + in-place per-block bases ===========
__global__ __launch_bounds__(512) void bucket_scan_kernel(
    int* __restrict__ blkhistD, int* __restrict__ blkhistS,
    int* __restrict__ bstart_d, int* __restrict__ bstart_s) {
  int* hist = (blockIdx.x == 0) ? blkhistD : blkhistS;
  int* bst  = (blockIdx.x == 0) ? bstart_d : bstart_s;
  int u = (int)threadIdx.x;
  int tot = 0;
  if (u < NBUCK) {
    for (int blk = 0; blk < P1B; ++blk) tot += hist[blk * NBUCK + u];
  }
  __shared__ int smA[512];
  __shared__ int smB[512];
  smA[u] = tot;
  __syncthreads();
  int* a = smA;
  int* bq = smB;
  for (int off = 1; off < 512; off <<= 1) {
    int v = a[u];
    if (u >= off) v += a[u - off];
    bq[u] = v;
    __syncthreads();
    int* tmp = a; a = bq; bq = tmp;
  }
  int excl = a[u] - tot;
  if (u <= NBUCK) bst[u] = excl;  // u==NBUCK: tot==0 -> excl == total
  if (u < NBUCK) {
    int off2 = excl;
    for (int blk = 0; blk < P1B; ++blk) {
      int h = hist[blk * NBUCK + u];
      hist[blk * NBUCK + u] = off2;
      off2 += h;
    }
  }
}

// =============== P3: scatter edges into bucket-partitioned arrays ============
__global__ __launch_bounds__(256) void part_scatter_kernel(
    const int* __restrict__ ei, const int* __restrict__ blkbaseD,
    const int* __restrict__ blkbaseS,
    unsigned int* __restrict__ edstP, int* __restrict__ esrc) {
  __shared__ int cD[NBUCK];
  __shared__ int cS[NBUCK];
  int b = (int)blockIdx.x;
  int t = (int)threadIdx.x;
  for (int i = t; i < NBUCK; i += 256) {
    cD[i] = blkbaseD[b * NBUCK + i];
    cS[i] = blkbaseS[b * NBUCK + i];
  }
  __syncthreads();
  int base_e = b * EPB;
  for (int s = 0; s < EPB / 1024; ++s) {
    int e4 = base_e + s * 1024 + t * 4;
    if (e4 < N_EDGES) {
      int4 s4 = *(const int4*)(ei + e4);
      int4 d4 = *(const int4*)(ei + N_EDGES + e4);
      int ss[4] = {s4.x, s4.y, s4.z, s4.w};
      int dd[4] = {d4.x, d4.y, d4.z, d4.w};
#pragma unroll
      for (int j = 0; j < 4; ++j) {
        if ((unsigned)ss[j] < N_NODES) {
          int slot = atomicAdd(&cS[ss[j] >> 8], 1);
          esrc[slot] = ss[j];
        }
        if ((unsigned)dd[j] < N_NODES) {
          int slot = atomicAdd(&cD[dd[j] >> 8], 1);
          edstP[slot] = ((unsigned int)ss[j] << 8) | ((unsigned int)dd[j] & 255u);
        }
      }
    }
  }
}

// =============== P4: per-bucket counting sort -> rowptr/col/norms ============
__global__ __launch_bounds__(256) void csr_kernel(
    const unsigned int* __restrict__ edstP, const int* __restrict__ esrc,
    const int* __restrict__ bstart_d, const int* __restrict__ bstart_s,
    int* __restrict__ rowptr, int* __restrict__ colx,
    float* __restrict__ norm_in, float* __restrict__ norm_out) {
  __shared__ int lc[256];
  __shared__ int smA[256];
  __shared__ int smB[256];
  int b = (int)blockIdx.x;
  int t = (int)threadIdx.x;
  if (b < NBUCK) {
    int node0 = b << 8;
    int base = bstart_d[b];
    int end  = bstart_d[b + 1];
    lc[t] = 0;
    __syncthreads();
    for (int i = base + t; i < end; i += 256) {
      unsigned int p = edstP[i];
      atomicAdd(&lc[p & 255u], 1);
    }
    __syncthreads();
    int my = lc[t];
    smA[t] = my;
    __syncthreads();
    int* a = smA;
    int* bq = smB;
    for (int off = 1; off < 256; off <<= 1) {
      int v = a[t];
      if (t >= off) v += a[t - off];
      bq[t] = v;
      __syncthreads();
      int* tmp = a; a = bq; bq = tmp;
    }
    int excl = a[t] - my;
    int n = node0 + t;
    if (n <= N_NODES) rowptr[n] = base + excl;
    if (n < N_NODES) {
      int c = my < 1 ? 1 : my;
      norm_in[n] = rsqrtf((float)c);
    }
    __syncthreads();
    lc[t] = base + excl;  // per-node cursor
    __syncthreads();
    for (int i = base + t; i < end; i += 256) {
      unsigned int p = edstP[i];
      int slot = atomicAdd(&lc[p & 255u], 1);
      colx[slot] = (int)(p >> 8);
    }
  } else {
    int bb = b - NBUCK;
    int node0 = bb << 8;
    int base = bstart_s[bb];
    int end  = bstart_s[bb + 1];
    lc[t] = 0;
    __syncthreads();
    for (int i = base + t; i < end; i += 256) {
      atomicAdd(&lc[esrc[i] - node0], 1);
    }
    __syncthreads();
    int n = node0 + t;
    if (n < N_NODES) {
      int c = lc[t] < 1 ? 1 : lc[t];
      norm_out[n] = rsqrtf((float)c);
    }
  }
}

// ------- SpMM core: 8 lanes per node, 4-deep unconditional gathers -----------
__device__ __forceinline__ void accum8f(uint4 v, float no, float acc[8]) {
  float lo, hi;
  unpack_bf2(v.x, lo, hi); acc[0] = fmaf(lo, no, acc[0]); acc[1] = fmaf(hi, no, acc[1]);
  unpack_bf2(v.y, lo, hi); acc[2] = fmaf(lo, no, acc[2]); acc[3] = fmaf(hi, no, acc[3]);
  unpack_bf2(v.z, lo, hi); acc[4] = fmaf(lo, no, acc[4]); acc[5] = fmaf(hi, no, acc[5]);
  unpack_bf2(v.w, lo, hi); acc[6] = fmaf(lo, no, acc[6]); acc[7] = fmaf(hi, no, acc[7]);
}

// gather with per-src norm_out scale; cols guaranteed valid by our CSR build
__device__ __forceinline__ void spmm_gather8s(const unsigned short* __restrict__ hs,
                                              const int* __restrict__ col,
                                              const float* __restrict__ no,
                                              int e0, int e1, int dim0,
                                              float acc[8]) {
  int e = e0;
  for (; e + 4 <= e1; e += 4) {
    int c0 = col[e], c1 = col[e + 1], c2 = col[e + 2], c3 = col[e + 3];
    float n0 = no[c0], n1 = no[c1], n2 = no[c2], n3 = no[c3];
    uint4 v0 = *(const uint4*)(hs + ((size_t)c0 << 6) + dim0);
    uint4 v1 = *(const uint4*)(hs + ((size_t)c1 << 6) + dim0);
    uint4 v2 = *(const uint4*)(hs + ((size_t)c2 << 6) + dim0);
    uint4 v3 = *(const uint4*)(hs + ((size_t)c3 << 6) + dim0);
    accum8f(v0, n0, acc);
    accum8f(v1, n1, acc);
    accum8f(v2, n2, acc);
    accum8f(v3, n3, acc);
  }
  for (; e < e1; ++e) {
    int c = col[e];
    uint4 v = *(const uint4*)(hs + ((size_t)c << 6) + dim0);
    accum8f(v, no[c], acc);
  }
}

__device__ __forceinline__ void accum8(uint4 v, float acc[8]) {
  float lo, hi;
  unpack_bf2(v.x, lo, hi); acc[0] += lo; acc[1] += hi;
  unpack_bf2(v.y, lo, hi); acc[2] += lo; acc[3] += hi;
  unpack_bf2(v.z, lo, hi); acc[4] += lo; acc[5] += hi;
  unpack_bf2(v.w, lo, hi); acc[6] += lo; acc[7] += hi;
}

__device__ __forceinline__ void spmm_gather8(const unsigned short* __restrict__ hs,
                                             const int* __restrict__ col,
                                             int e0, int e1, int dim0,
                                             float acc[8]) {
  int e = e0;
  for (; e + 4 <= e1; e += 4) {
    int c0 = col[e], c1 = col[e + 1], c2 = col[e + 2], c3 = col[e + 3];
    uint4 v0 = *(const uint4*)(hs + ((size_t)c0 << 6) + dim0);
    uint4 v1 = *(const uint4*)(hs + ((size_t)c1 << 6) + dim0);
    uint4 v2 = *(const uint4*)(hs + ((size_t)c2 << 6) + dim0);
    uint4 v3 = *(const uint4*)(hs + ((size_t)c3 << 6) + dim0);
    accum8(v0, acc);
    accum8(v1, acc);
    accum8(v2, acc);
    accum8(v3, acc);
  }
  for (; e < e1; ++e) {
    int c = col[e];
    uint4 v = *(const uint4*)(hs + ((size_t)c << 6) + dim0);
    accum8(v, acc);
  }
}

// ====== Fused SpMM layer-1 + gemm2: block = 32 nodes =========================
// Phase 1 (8 lanes/node): h1 = relu(Agg(hs1raw[src]*norm_out[src])*norm_in+b1)
// staged as bf16 into padded LDS [32][72] (2-way bank aliasing only).
// Phase 2: 4 waves compute hs2 = (h1 @ W2) * norm_out via MFMA quadrants
// (wave w: 16-node tile w>>1, col-tiles {2*(w&1), 2*(w&1)+1}); identical op
// order to the old standalone gemm2 bf16 path -> bit-identical results.
__global__ __launch_bounds__(256) void spmm_gemm_kernel(
    const unsigned short* __restrict__ hs,
    const int* __restrict__ rowptr, const int* __restrict__ col,
    const float* __restrict__ norm_out, const float* __restrict__ norm_in,
    const float* __restrict__ b1f,
    const unsigned short* __restrict__ W2hf,
    const unsigned short* __restrict__ W2lf,
    unsigned short* __restrict__ hs2) {
  __shared__ unsigned short h1s[32][72];  // 72 = 64 + 8 pad
  int t = (int)threadIdx.x;
  // ---- phase 1: SpMM (grid is exact: 3125*32 == 100000, no tail) ----
  int n = (int)blockIdx.x * 32 + (t >> 3);
  int dim0 = (t & 7) << 3;
  int e0 = rowptr[n], e1 = rowptr[n + 1];
  if (e0 < 0) e0 = 0;
  if (e1 > N_EDGES) e1 = N_EDGES;
  float acc[8];
#pragma unroll
  for (int i = 0; i < 8; ++i) acc[i] = 0.f;
  spmm_gather8s(hs, col, norm_out, e0, e1, dim0, acc);
  float nin = norm_in[n];
  unsigned int pk[4];
#pragma unroll
  for (int i = 0; i < 4; ++i) {
    float vlo = fmaxf(acc[2 * i] * nin + b1f[dim0 + 2 * i], 0.f);
    float vhi = fmaxf(acc[2 * i + 1] * nin + b1f[dim0 + 2 * i + 1], 0.f);
    pk[i] = (unsigned int)f2bf(vlo) | ((unsigned int)f2bf(vhi) << 16);
  }
  *(uint4*)&h1s[t >> 3][dim0] = make_uint4(pk[0], pk[1], pk[2], pk[3]);
  __syncthreads();
  // ---- phase 2: MFMA h1 @ W2 ----
  int wv = t >> 6;             // wave 0..3
  int lane = t & 63;
  int mloc = (wv >> 1) << 4;   // node sub-tile 0 or 16
  int ct0 = (wv & 1) << 1;     // col-tiles {0,1} or {2,3}
  int row = lane & 15, kg = lane >> 4;
  f32x4 a0 = {0.f, 0.f, 0.f, 0.f};
  f32x4 a1 = {0.f, 0.f, 0.f, 0.f};
  const short8v* wh = (const short8v*)W2hf + lane;
  const short8v* wl = (const short8v*)W2lf + lane;
#pragma unroll
  for (int kt = 0; kt < 2; ++kt) {
    short8v av = *(const short8v*)&h1s[mloc + row][kt * 32 + (kg << 3)];
    a0 = mfma16(av, wh[(kt * 4 + ct0) * 64], a0);
    a1 = mfma16(av, wh[(kt * 4 + ct0 + 1) * 64], a1);
    a0 = mfma16(av, wl[(kt * 4 + ct0) * 64], a0);
    a1 = mfma16(av, wl[(kt * 4 + ct0 + 1) * 64], a1);
  }
  int colc = lane & 15;
#pragma unroll
  for (int i = 0; i < 4; ++i) {
    int ng = (int)blockIdx.x * 32 + mloc + (kg << 2) + i;
    float s = norm_out[ng];
    size_t rb = (size_t)ng << 6;
    hs2[rb + (ct0 << 4) + colc]       = f2bf(a0[i] * s);
    hs2[rb + ((ct0 + 1) << 4) + colc] = f2bf(a1[i] * s);
  }
}

// ------- SpMM layer-2 fused with attention gate; 8 lanes per node ------------
__global__ __launch_bounds__(256) void spmm_attn_kernel(
    const unsigned short* __restrict__ hs,
    const int* __restrict__ rowptr, const int* __restrict__ col,
    const float* __restrict__ norm_in, const float* __restrict__ b2f,
    const float* __restrict__ attnWf, const float* __restrict__ attnbf,
    void* __restrict__ out_base, unsigned short* __restrict__ gated,
    const int* __restrict__ flag) {
  int mode = flag[0];
  int n = (int)(blockIdx.x * 32 + (threadIdx.x >> 3));
  int dim0 = ((int)threadIdx.x & 7) << 3;
  if (n >= N_NODES) return;
  int e0 = rowptr[n], e1 = rowptr[n + 1];
  if (e0 < 0) e0 = 0;
  if (e1 > N_EDGES) e1 = N_EDGES;
  float acc[8];
#pragma unroll
  for (int i = 0; i < 8; ++i) acc[i] = 0.f;
  spmm_gather8(hs, col, e0, e1, dim0, acc);
  float nin = norm_in[n];
  float vv[8];
  float p = 0.f;
#pragma unroll
  for (int i = 0; i < 8; ++i) {
    vv[i] = fmaxf(acc[i] * nin + b2f[dim0 + i], 0.f);  // h2[n][dim0+i]
    p += vv[i] * attnWf[dim0 + i];
  }
#pragma unroll
  for (int m = 1; m <= 4; m <<= 1) p += __shfl_xor(p, m, 64);
  float logit = p + attnbf[0];
  float hwv = 1.f / (1.f + __expf(-logit));
  if ((threadIdx.x & 7) == 0) {
    if (mode) ((unsigned short*)out_base)[N_GRAPHS * N_CLASSES + n] = f2bf(hwv);
    else      ((float*)out_base)[N_GRAPHS * N_CLASSES + n] = hwv;
  }
  unsigned int pk[4];
#pragma unroll
  for (int i = 0; i < 4; ++i) {
    pk[i] = (unsigned int)f2bf(vv[2 * i] * hwv) |
            ((unsigned int)f2bf(vv[2 * i + 1] * hwv) << 16);
  }
  *(uint4*)(gated + ((size_t)n << 6) + dim0) = make_uint4(pk[0], pk[1], pk[2], pk[3]);
}

// -------- pool: 64 graphs x 32 slices, partial sums ----------
__global__ __launch_bounds__(256) void pool_kernel(const unsigned short* __restrict__ gated,
                                                   const int* __restrict__ gstart,
                                                   float* __restrict__ gpart) {
  int g = (int)blockIdx.x >> 5;         // graph
  int s = (int)blockIdx.x & 31;         // slice
  int dim = (int)threadIdx.x & 63;
  int rsel = (int)threadIdx.x >> 6;
  int r0 = gstart[g], r1 = gstart[g + 1];
  if (r0 < 0) r0 = 0;
  if (r1 > N_NODES) r1 = N_NODES;
  int len = r1 - r0;
  if (len < 0) len = 0;
  int a = r0 + (int)(((long long)len * s) >> 5);
  int bnd = r0 + (int)(((long long)len * (s + 1)) >> 5);
  float acc = 0.f;
  for (int r = a + rsel; r < bnd; r += 4)
    acc += bf2f(gated[((size_t)r << 6) + dim]);
  __shared__ float sm[256];
  sm[threadIdx.x] = acc;
  __syncthreads();
  if (threadIdx.x < 64)
    gpart[((size_t)blockIdx.x << 6) + dim] =
        sm[dim] + sm[64 + dim] + sm[128 + dim] + sm[192 + dim];
}

// ---- final (merged slice-reduce + classifier): 1 block, 640 threads ---------
__global__ __launch_bounds__(640) void final_kernel(const float* __restrict__ gpart,
                                                    const int* __restrict__ gstart,
                                                    const float* __restrict__ clsWf,
                                                    const float* __restrict__ clsbf,
                                                    void* __restrict__ out_base,
                                                    const int* __restrict__ flag) {
  __shared__ float gs[N_GRAPHS * HID];
  int t = (int)threadIdx.x;
  for (int idx = t; idx < N_GRAPHS * HID; idx += 640) {
    int g = idx >> 6, d = idx & 63;
    float a = 0.f;
#pragma unroll
    for (int s = 0; s < POOL_SLICES; ++s)
      a += gpart[(((size_t)(g << 5) + s) << 6) + d];
    gs[idx] = a;
  }
  __syncthreads();
  int mode = flag[0];
  if (t >= N_GRAPHS * N_CLASSES) return;
  int g = t / N_CLASSES, c = t - g * N_CLASSES;
  int cg = gstart[g + 1] - gstart[g];
  if (cg < 1) cg = 1;
  float inv = 1.f / (float)cg;
  float acc = 0.f;
#pragma unroll
  for (int d = 0; d < HID; ++d) acc += gs[(g << 6) + d] * clsWf[d * N_CLASSES + c];
  float r = acc * inv + clsbf[c];
  if (mode) ((unsigned short*)out_base)[t] = f2bf(r);
  else      ((float*)out_base)[t] = r;
}

extern "C" void kernel_launch(void* const* d_in, const int* in_sizes, int n_in,
                              void* d_out, int out_size, void* d_ws, size_t ws_size,
                              hipStream_t stream) {
  const void* x     = d_in[0];
  const int*  ei    = (const int*)d_in[1];
  const int*  gid   = (const int*)d_in[2];
  const void* W1    = d_in[3];
  const void* b1    = d_in[4];
  const void* W2    = d_in[5];
  const void* b2    = d_in[6];
  const void* attnW = d_in[7];
  const void* attnb = d_in[8];
  const void* clsW  = d_in[9];
  const void* clsb  = d_in[10];

  if (ws_size < (size_t)WS_NEED) {
    fallback_kernel<<<(out_size + 255) / 256, 256, 0, stream>>>(
        (unsigned short*)d_out, out_size);
    return;
  }

  // ---- workspace layout (bytes). Every buffer fully written by a producer. ----
  char* w = (char*)d_ws;
  int*   flag     = (int*)(w + 0);          //      64 (2 used, wcvt writes)
  int*   gstart   = (int*)(w + 64);         //     512 (gbound writes all)
  int*   bstart_d = (int*)(w + 16960);      //    1600 (392 used)
  int*   bstart_s = (int*)(w + 18560);      //    1600
  int*   blkhD    = (int*)(w + 20160);      //  306560 (196*391 ints)
  int*   blkhS    = (int*)(w + 326720);     //  306560
  int*   rowptr   = (int*)(w + 633280);     //  400064 (100001 used)
  float* norm_out = (float*)(w + 1033344);  //  400000
  float* norm_in  = (float*)(w + 1433344);  //  400000
  unsigned short* W1hf = (unsigned short*)(w + 1833344);  // 16384
  unsigned short* W1lf = (unsigned short*)(w + 1849728);  // 16384
  unsigned short* W2hf = (unsigned short*)(w + 1866112);  //  8192
  unsigned short* W2lf = (unsigned short*)(w + 1874304);  //  8192 -> 1882496
  float* b1f      = (float*)(w + 1882496);  //     256
  float* b2f      = (float*)(w + 1882752);  //     256
  float* attnWf   = (float*)(w + 1883008);  //     256
  float* attnbf   = (float*)(w + 1883264);  //      64
  float* clsWf    = (float*)(w + 1883328);  //    2560
  float* clsbf    = (float*)(w + 1885888);  //      64 -> 1885952
  int*   colx     = (int*)(w + 1885952);    //  6400000 -> 8285952
  unsigned int* edstP = (unsigned int*)(w + 8285952);   // 6400000 -> 14685952
  int*   esrc     = (int*)(w + 14685952);   //  6400000 -> 21085952
  unsigned short* bufA = (unsigned short*)(w + 21085952); // 12800000 -> 33885952
  // bufB aliases edstP+esrc (dead after csr; spmm_gemm writes after csr).
  unsigned short* bufB = (unsigned short*)(w + 8285952);  // 12800000
  // gpart aliases blkh region (dead after part_scatter reads the bases; pool
  // writes it only after spmm_attn). 524288B <= 613120 available.
  float* gpart    = (float*)(w + 20160);

  // wcvt self-probes x's dtype and writes flag; converts weights to fragments.
  wcvt_kernel<<<32, 256, 0, stream>>>((const unsigned short*)x, W1, W2, b1, b2,
                                      attnW, attnb, clsW, clsb, W1hf, W1lf,
                                      W2hf, W2lf, b1f, b2f, attnWf, attnbf,
                                      clsWf, clsbf, flag);

  // FAT-A: bucket histograms | gemm1_raw (unscaled x@W1, MFMA) | graph bounds
  fatA_kernel<<<P1B + GEMM_BLOCKS + GB_BLOCKS, 256, 0, stream>>>(
      ei, blkhD, blkhS, gid, gstart, x, W1hf, W1lf, bufA, flag);

  bucket_scan_kernel<<<2, 512, 0, stream>>>(blkhD, blkhS, bstart_d, bstart_s);
  part_scatter_kernel<<<P1B, 256, 0, stream>>>(ei, blkhD, blkhS, edstP, esrc);
  csr_kernel<<<2 * NBUCK, 256, 0, stream>>>(edstP, esrc, bstart_d, bstart_s,
                                            rowptr, colx, norm_in, norm_out);

  // fused layer-1 SpMM + gemm2: bufA (hs1raw) -> bufB (hs2), via LDS h1 tile
  spmm_gemm_kernel<<<SPMM_BLOCKS, 256, 0, stream>>>(
      bufA, rowptr, colx, norm_out, norm_in, b1f, W2hf, W2lf, bufB);

  // layer-2 aggregation + attention gate: bufB (hs2) -> bufA (gated rows)
  spmm_attn_kernel<<<SPMM_BLOCKS, 256, 0, stream>>>(
      bufB, rowptr, colx, norm_in, b2f, attnWf, attnbf, d_out, bufA, flag);

  // pooling: 2048 slice blocks -> partials; final merges reduce + classifier
  pool_kernel<<<N_GRAPHS * POOL_SLICES, 256, 0, stream>>>(bufA, gstart, gpart);
  final_kernel<<<1, 640, 0, stream>>>(gpart, gstart, clsWf, clsbf, d_out, flag);
}